// Round 13
// baseline (485.209 us; speedup 1.0000x reference)
//
#include <hip/hip_runtime.h>

// LSTM B=2048,T=512,I=5,H=128 + linear -> [B,1], fp32 in/out.
// Round 13 = r12 (344us) with the block barrier replaced by DATAFLOW SYNC.
// r12 counters: MfmaUtil 47 + VALUBusy 49 = 96% -> SIMD issue saturated but
// phase-SERIAL (waves lockstep: MFMA pipe idles during cell phase and vice
// versa). m114: MFMA+VALU co-issue across waves on one SIMD - needs waves in
// DIFFERENT phases. Mechanism: wave w is the unique producer of h cols
// [16w,16w+16). Per-wave monotonic counters flags[8] in LDS:
//   producer: write h(t+1) -> threadfence_block -> flags[w]=t+1 (lane 0)
//   consumer: before MFMA chunk c of step t, spin until flags[2c],flags[2c+1]
//             >= t (volatile broadcast reads, wave-uniform branch, s_sleep).
// WAR-safe with 2 h buffers: flag[v]>=t => v finished step t-1 => v fully
// read h(t-1), so overwriting hbuf[(t+1)&1] (=h(t-1) slot) is safe. Acyclic
// dependency order -> deadlock-free. Waves de-phase (chunk-3 consumers give
// those producers ~230cyc slack) -> cross-wave MFMA/VALU overlap.
// Everything else = r12: 256 blocks x 8 batches, NT=512, row-permuted direct
// cell ownership, K=16 x/bias MFMA, folded scales, f16 ops (absmax
// 4.882812e-4), waves_per_eu(2,2). Dead-ends on record: BT=16 halves CUs;
// 1024-thr blocks pin VGPR@64 -> spill; BT=4 doubles MFMA padding; K-split
// pacc +2e7 conflicts; source-order/SGB interleave ~neutral (r11/r12).

#define HH 128
#define II 5
#define TT 512
#define BT 8
#define NT 512
#define KS 136             // hbuf row stride in f16
#define XT (TT * 8 + 8)    // xs per-batch stride in f16
#define HB (16 * KS)       // hbuf buffer stride in f16 elems

typedef __attribute__((ext_vector_type(8))) _Float16 half8;
typedef __attribute__((ext_vector_type(4))) _Float16 half4;
typedef __attribute__((ext_vector_type(4))) float f32x4;

#define SIG(u) __builtin_amdgcn_rcpf(1.0f + __builtin_amdgcn_exp2f(u))
#define MF32(A, B, C) __builtin_amdgcn_mfma_f32_16x16x32_f16((A), (B), (C), 0, 0, 0)
#define MF16(A, B, C) __builtin_amdgcn_mfma_f32_16x16x16f16((A), (B), (C), 0, 0, 0)

// One timestep. PB = h read buffer (compile-time 0/1), LAST = peeled final.
// tcur = runtime step index; incremented at the end.
#define STEP(PB, LAST) {                                                        \
    /* x/bias K16 chains first: no h dependency, keeps MFMA pipe warm */        \
    f32x4 a0 = MF16(ax4, wfx[0], zero4);                                        \
    f32x4 a1 = MF16(ax4, wfx[1], zero4);                                        \
    f32x4 a2 = MF16(ax4, wfx[2], zero4);                                        \
    f32x4 a3 = MF16(ax4, wfx[3], zero4);                                        \
    const _Float16* hp = hrd + (PB) * HB;                                       \
    _Pragma("unroll")                                                           \
    for (int c = 0; c < 4; ++c) {                                               \
        for (;;) {                      /* wait producers of h cols 32c..32c+32 */\
            int f0 = vfl[2 * c];                                                \
            int f1 = vfl[2 * c + 1];                                            \
            if (f0 >= tcur && f1 >= tcur) break;                                \
            __builtin_amdgcn_s_sleep(1);                                        \
        }                                                                       \
        half8 ah = *reinterpret_cast<const half8*>(hp + 32 * c);                \
        a0 = MF32(ah, wf[0][c], a0);                                            \
        a1 = MF32(ah, wf[1][c], a1);                                            \
        a2 = MF32(ah, wf[2][c], a2);                                            \
        a3 = MF32(ah, wf[3][c], a3);                                            \
    }                                                                           \
    if (!(LAST)) {                      /* prefetch ax(t+1): static xs */       \
        xcur += xinc;                                                           \
        ax4 = *reinterpret_cast<const half4*>(xcur);                            \
    }                                                                           \
    float iv0 = SIG(a0[0]);                                                     \
    float iv1 = SIG(a0[1]);                                                     \
    float fv0 = SIG(a1[0]);                                                     \
    float fv1 = SIG(a1[1]);                                                     \
    float gv0 = 1.0f - 2.0f * SIG(a2[0]);                                       \
    float ov0 = SIG(a3[0]);                                                     \
    cc0 = fv0 * cc0 + iv0 * gv0;                                                \
    float hv0 = ov0 * (1.0f - 2.0f * SIG(2.88539008f * cc0));                   \
    float gv1 = 1.0f - 2.0f * SIG(a2[1]);                                       \
    float ov1 = SIG(a3[1]);                                                     \
    cc1 = fv1 * cc1 + iv1 * gv1;                                                \
    float hv1 = ov1 * (1.0f - 2.0f * SIG(2.88539008f * cc1));                   \
    if (LAST) {                                                                 \
        hsc[bcell][hcol] = hv0; hsc[bcell + 1][hcol] = hv1;                     \
    } else {                                                                    \
        _Float16* wp = hwr + ((PB) ^ 1) * HB;                                   \
        wp[0]  = (_Float16)hv0;                                                 \
        wp[KS] = (_Float16)hv1;                                                 \
        __threadfence_block();          /* h writes visible before flag bump */ \
        if (lane == 0) vfl[w] = tcur + 1;                                       \
    }                                                                           \
    ++tcur;                                                                     \
}

__global__ __launch_bounds__(NT)
__attribute__((amdgpu_waves_per_eu(2, 2)))   // 256-VGPR budget: spill guard
void lstm_r13(const float* __restrict__ x,      // [B,T,I]
              const float* __restrict__ W_ih,   // [4H,I]
              const float* __restrict__ W_hh,   // [4H,H]
              const float* __restrict__ b_ih,   // [4H]
              const float* __restrict__ b_hh,   // [4H]
              const float* __restrict__ W_lin,  // [H]
              const float* __restrict__ b_lin,  // [1]
              float* __restrict__ out,          // [B]
              int B)
{
    __shared__ __align__(16) _Float16 hbuf[2][16][KS];  // rows 2,3 mod 4 stay 0
    __shared__ __align__(16) _Float16 zrow[KS];         // zeros for pad-row lanes
    __shared__ __align__(16) _Float16 xs[BT * XT];      // 65.7 KB staged x (f16)
    __shared__ float hsc[BT][HH + 4];                   // final fp32 h
    __shared__ int flags[8];                            // per-wave step counters

    const int tid  = threadIdx.x;
    const int b0   = blockIdx.x * BT;
    const int lane = tid & 63;
    const int w    = tid >> 6;        // 0..7 -> col group / producer id
    const int n    = lane & 15;       // A row index / D col
    const int q    = lane >> 4;
    const int q8   = q * 8;
    const int hcol = w * 16 + n;      // this wave's gate columns

    volatile int* vfl = flags;

    // ---- W_hh frags, f16, B-layout (lane holds W^T[k=q8+e][col n]), scaled --
    half8 wf[4][4];
    half4 wfx[4];                     // x/bias chunk, K=16: k = q*4+e
    #pragma unroll
    for (int g = 0; g < 4; ++g) {
        const float sc = (g == 2) ? 2.88539008f : -1.44269504f;
        const int j = g * HH + hcol;
        #pragma unroll
        for (int kc = 0; kc < 4; ++kc) {
            const float* p = W_hh + (size_t)j * HH + kc * 32 + q8;
            #pragma unroll
            for (int e = 0; e < 8; ++e) wf[g][kc][e] = (_Float16)(p[e] * sc);
        }
        #pragma unroll
        for (int e = 0; e < 4; ++e) {
            const int k = q * 4 + e;
            float v = 0.0f;
            if (k < II)       v = W_ih[j * II + k];
            else if (k == II) v = b_ih[j] + b_hh[j];
            wfx[g][e] = (_Float16)(v * sc);
        }
    }

    // ---- zero LDS + flags ---------------------------------------------------
    for (int idx = tid; idx < 2 * 16 * KS; idx += NT)
        (&hbuf[0][0][0])[idx] = (_Float16)0.0f;
    if (tid < KS) zrow[tid] = (_Float16)0.0f;
    if (tid < 8) flags[tid] = 0;                  // h(0) "written" by everyone
    for (int idx = tid; idx < BT * XT; idx += NT)
        xs[idx] = (_Float16)0.0f;
    __syncthreads();

    // ---- stage x (f16) + constant-1.0 bias column in slot 5 -----------------
    {
        const int lb = tid & 63, bb = tid >> 6;     // 64 threads per batch
        if (b0 + bb < B) {
            const float* xb = x + (size_t)(b0 + bb) * TT * II;
            for (int e = lb * 4; e < TT * II; e += 256) {
                float4 v = *reinterpret_cast<const float4*>(xb + e);
                float vv[4] = {v.x, v.y, v.z, v.w};
                #pragma unroll
                for (int u = 0; u < 4; ++u) {
                    const int ee = e + u;
                    xs[bb * XT + (ee / 5) * 8 + (ee % 5)] = (_Float16)vv[u];
                }
            }
        }
        for (int s = tid; s < BT * TT; s += NT)
            xs[(s >> 9) * XT + (s & 511) * 8 + 5] = (_Float16)1.0f;
    }
    __syncthreads();                               // last block-wide barrier

    // ---- loop-invariant state ----------------------------------------------
    // Row permutation (r10): batch b -> A-row rho(b) = (b>>1)*4 + (b&1);
    // C/D rows q*4+{0,1} = batches {2q, 2q+1} -> direct cell ownership.
    const int bcell = 2 * q;
    float cc0 = 0.f, cc1 = 0.f;
    const f32x4 zero4 = {0.f, 0.f, 0.f, 0.f};
    const bool xreal = ((n & 2) == 0);
    const int  bofn  = (n >> 2) * 2 + (n & 1);      // batch carried by A-row n
    const _Float16* hrd  = &hbuf[0][n][0] + q8;     // unconditional (pad rows = 0)
    _Float16*       hwr  = &hbuf[0][q * 4][0] + hcol;
    const _Float16* xcur = xreal ? (&xs[bofn * XT] + q * 4) : (&zrow[0] + q * 4);
    const int       xinc = xreal ? 8 : 0;

    half4 ax4 = *reinterpret_cast<const half4*>(xcur);   // t=0 preload
    int tcur = 0;

    #pragma unroll 1
    for (int k = 0; k < (TT - 2) / 2; ++k) {
        STEP(0, false);
        STEP(1, false);
    }
    STEP(0, false);     // t = 510
    STEP(1, true);      // t = 511, peeled: fp32 hsc write, no flag
    __syncthreads();    // hsc complete before epilogue

    // ---- epilogue: out[b0+w] = hsc[w,:] . W_lin + b_lin ---------------------
    float p = hsc[w][lane] * W_lin[lane] + hsc[w][lane + 64] * W_lin[lane + 64];
    #pragma unroll
    for (int off = 32; off > 0; off >>= 1) p += __shfl_down(p, off, 64);
    if (lane == 0 && (b0 + w) < B) out[b0 + w] = p + b_lin[0];
}

extern "C" void kernel_launch(void* const* d_in, const int* in_sizes, int n_in,
                              void* d_out, int out_size, void* d_ws, size_t ws_size,
                              hipStream_t stream) {
    const float* x     = (const float*)d_in[0];
    const float* W_ih  = (const float*)d_in[1];
    const float* W_hh  = (const float*)d_in[2];
    const float* b_ih  = (const float*)d_in[3];
    const float* b_hh  = (const float*)d_in[4];
    const float* W_lin = (const float*)d_in[5];
    const float* b_lin = (const float*)d_in[6];
    float* out = (float*)d_out;

    const int B = in_sizes[0] / (TT * II);          // 2048
    const int grid = (B + BT - 1) / BT;             // 256 blocks, 1 per CU
    lstm_r13<<<grid, NT, 0, stream>>>(x, W_ih, W_hh, b_ih, b_hh,
                                      W_lin, b_lin, out, B);
}

// Round 14
// 404.122 us; speedup vs baseline: 1.2007x; 1.2007x over previous
//
#include <hip/hip_runtime.h>

// LSTM B=2048,T=512,I=5,H=128 + linear -> [B,1], fp32 in/out.
// Round 14: ANTI-PHASE VIA 2 BLOCKS/CU. r12 (344us) is phase-serial: per
// SIMD-step MFMA 776 + VALU 740 alternate because both resident waves share
// one block barrier. Issue-port math says a de-phased schedule = max(740,776)
// ~850cyc (~190us). In-block de-sync failed (r13: +660cyc poll cost, all-to-all
// deps). Here: NT=256 (4 waves), BT=8, grid=512 -> 2 independent blocks/CU.
// Each wave owns hj in [32w,32w+32): 8 gate-tiles, 40 MFMA/wave-step, 4
// cells/lane (per-batch pipe demand unchanged; A-frag ds_reads amortize 2x).
// The 2 waves/SIMD now come from DIFFERENT blocks - no shared barrier, phases
// drift/self-organize to anti-phase -> cross-wave MFMA/VALU overlap (m114).
// LDS 78.9KB/block -> two fit in 160KB (r12 measured 79360B). VGPR ~210 under
// waves_per_eu(2,2)'s 256 budget. Failure signatures: Occupancy ~12% = only
// 1 block/CU resident; WRITE_SIZE >> 8KB = spill.
// Proven parts kept: row-permuted direct cell ownership (no shuffles), dbuf h
// + 1 barrier/step, K=16 x/bias MFMA, folded activation scales, peeled last
// step, f16 operands (absmax 4.882812e-4 exactly).

#define HH 128
#define II 5
#define TT 512
#define BT 8
#define NT 256
#define KS 136             // hbuf row stride in f16
#define XT (TT * 8 + 8)    // xs per-batch stride in f16
#define HB (16 * KS)       // hbuf buffer stride in f16 elems

typedef __attribute__((ext_vector_type(8))) _Float16 half8;
typedef __attribute__((ext_vector_type(4))) _Float16 half4;
typedef __attribute__((ext_vector_type(4))) float f32x4;

#define SIG(u) __builtin_amdgcn_rcpf(1.0f + __builtin_amdgcn_exp2f(u))
#define MF32(A, B, C) __builtin_amdgcn_mfma_f32_16x16x32_f16((A), (B), (C), 0, 0, 0)
#define MF16(A, B, C) __builtin_amdgcn_mfma_f32_16x16x16f16((A), (B), (C), 0, 0, 0)

// One timestep. PB = h read buffer (compile-time 0/1), LAST = peeled final.
// 8 tiles: [gate g][hj-half s]; acc rows q*4+{0,1} = batches {2q,2q+1}.
#define STEP(PB, LAST) {                                                        \
    const _Float16* hp = hrd + (PB) * HB;                                       \
    ah0 = *reinterpret_cast<const half8*>(hp);                                  \
    ah1 = *reinterpret_cast<const half8*>(hp + 32);                             \
    ah2 = *reinterpret_cast<const half8*>(hp + 64);                             \
    ah3 = *reinterpret_cast<const half8*>(hp + 96);                             \
    f32x4 acc[4][2];                                                            \
    _Pragma("unroll")                                                           \
    for (int g = 0; g < 4; ++g)                                                 \
        _Pragma("unroll")                                                       \
        for (int s = 0; s < 2; ++s) {                                           \
            acc[g][s] = MF16(ax4, wfx[g][s], zero4);                            \
            acc[g][s] = MF32(ah0, wf[g][s][0], acc[g][s]);                      \
            acc[g][s] = MF32(ah1, wf[g][s][1], acc[g][s]);                      \
            acc[g][s] = MF32(ah2, wf[g][s][2], acc[g][s]);                      \
            acc[g][s] = MF32(ah3, wf[g][s][3], acc[g][s]);                      \
        }                                                                       \
    if (!(LAST)) {                      /* prefetch ax(t+1): static xs */       \
        xcur += xinc;                                                           \
        ax4 = *reinterpret_cast<const half4*>(xcur);                            \
    }                                                                           \
    _Pragma("unroll")                                                           \
    for (int s = 0; s < 2; ++s) {                                               \
        _Pragma("unroll")                                                       \
        for (int jj = 0; jj < 2; ++jj) {                                        \
            float iv = SIG(acc[0][s][jj]);                                      \
            float fv = SIG(acc[1][s][jj]);                                      \
            float gv = 1.0f - 2.0f * SIG(acc[2][s][jj]);                        \
            float ov = SIG(acc[3][s][jj]);                                      \
            float& c = cc[s][jj];                                               \
            c = fv * c + iv * gv;                                               \
            float hv = ov * (1.0f - 2.0f * SIG(2.88539008f * c));               \
            if (LAST) {                                                         \
                hsc[2 * q + jj][w * 32 + s * 16 + n] = hv;                      \
            } else {                                                            \
                hwr[((PB) ^ 1) * HB + s * 16 + jj * KS] = (_Float16)hv;         \
            }                                                                   \
        }                                                                       \
    }                                                                           \
    __syncthreads();                                                            \
}

__global__ __launch_bounds__(NT)
__attribute__((amdgpu_waves_per_eu(2, 2)))   // 256-VGPR budget (wf=144 resident)
void lstm_r14(const float* __restrict__ x,      // [B,T,I]
              const float* __restrict__ W_ih,   // [4H,I]
              const float* __restrict__ W_hh,   // [4H,H]
              const float* __restrict__ b_ih,   // [4H]
              const float* __restrict__ b_hh,   // [4H]
              const float* __restrict__ W_lin,  // [H]
              const float* __restrict__ b_lin,  // [1]
              float* __restrict__ out,          // [B]
              int B)
{
    __shared__ __align__(16) _Float16 hbuf[2][16][KS];  // rows 2,3 mod 4 stay 0
    __shared__ __align__(16) _Float16 zrow[KS];         // zeros for pad-row lanes
    __shared__ __align__(16) _Float16 xs[BT * XT];      // 65.7 KB staged x (f16)
    __shared__ float hsc[BT][HH + 4];                   // final fp32 h

    const int tid  = threadIdx.x;
    const int b0   = blockIdx.x * BT;
    const int lane = tid & 63;
    const int w    = tid >> 6;        // 0..3 -> hj group [32w, 32w+32)
    const int n    = lane & 15;       // A row index / D col
    const int q    = lane >> 4;
    const int q8   = q * 8;

    // ---- W frags, f16, B-layout, scaled: 8 tiles = [gate][hj-half] ----------
    half8 wf[4][2][4];
    half4 wfx[4][2];                  // x/bias chunk, K=16: k = q*4+e
    #pragma unroll
    for (int g = 0; g < 4; ++g) {
        const float sc = (g == 2) ? 2.88539008f : -1.44269504f;
        #pragma unroll
        for (int s = 0; s < 2; ++s) {
            const int j = g * HH + w * 32 + s * 16 + n;
            #pragma unroll
            for (int kc = 0; kc < 4; ++kc) {
                const float* p = W_hh + (size_t)j * HH + kc * 32 + q8;
                #pragma unroll
                for (int e = 0; e < 8; ++e) wf[g][s][kc][e] = (_Float16)(p[e] * sc);
            }
            #pragma unroll
            for (int e = 0; e < 4; ++e) {
                const int k = q * 4 + e;
                float v = 0.0f;
                if (k < II)       v = W_ih[j * II + k];
                else if (k == II) v = b_ih[j] + b_hh[j];
                wfx[g][s][e] = (_Float16)(v * sc);
            }
        }
    }

    // ---- zero LDS -----------------------------------------------------------
    for (int idx = tid; idx < 2 * 16 * KS; idx += NT)
        (&hbuf[0][0][0])[idx] = (_Float16)0.0f;
    if (tid < KS) zrow[tid] = (_Float16)0.0f;
    for (int idx = tid; idx < BT * XT; idx += NT)
        xs[idx] = (_Float16)0.0f;
    __syncthreads();

    // ---- stage x (f16) + constant-1.0 bias column in slot 5 -----------------
    {
        const int lb = tid & 31, bb = tid >> 5;     // 32 threads per batch
        if (b0 + bb < B) {
            const float* xb = x + (size_t)(b0 + bb) * TT * II;
            for (int e = lb * 4; e < TT * II; e += 128) {
                float4 v = *reinterpret_cast<const float4*>(xb + e);
                float vv[4] = {v.x, v.y, v.z, v.w};
                #pragma unroll
                for (int u = 0; u < 4; ++u) {
                    const int ee = e + u;
                    xs[bb * XT + (ee / 5) * 8 + (ee % 5)] = (_Float16)vv[u];
                }
            }
        }
        for (int s = tid; s < BT * TT; s += NT)
            xs[(s >> 9) * XT + (s & 511) * 8 + 5] = (_Float16)1.0f;
    }
    __syncthreads();

    // ---- loop-invariant state ----------------------------------------------
    // Row permutation (r10): batch b -> A-row rho(b) = (b>>1)*4 + (b&1);
    // C/D rows q*4+{0,1} = batches {2q, 2q+1} -> direct cell ownership.
    float cc[2][2] = {{0.f, 0.f}, {0.f, 0.f}};
    const f32x4 zero4 = {0.f, 0.f, 0.f, 0.f};
    const bool xreal = ((n & 2) == 0);
    const int  bofn  = (n >> 2) * 2 + (n & 1);      // batch carried by A-row n
    const _Float16* hrd  = &hbuf[0][n][0] + q8;     // unconditional (pad rows = 0)
    _Float16*       hwr  = &hbuf[0][q * 4][0] + w * 32 + n;
    const _Float16* xcur = xreal ? (&xs[bofn * XT] + q * 4) : (&zrow[0] + q * 4);
    const int       xinc = xreal ? 8 : 0;

    half8 ah0, ah1, ah2, ah3;
    half4 ax4 = *reinterpret_cast<const half4*>(xcur);   // t=0 preload

    #pragma unroll 1
    for (int k = 0; k < (TT - 2) / 2; ++k) {
        STEP(0, false);
        STEP(1, false);
    }
    STEP(0, false);     // t = 510
    STEP(1, true);      // t = 511, peeled: fp32 hsc write, no prefetch

    // ---- epilogue: out[b] = hsc[b,:] . W_lin + b_lin (2 batches per wave) ---
    #pragma unroll
    for (int r = 0; r < 2; ++r) {
        const int bb = 2 * w + r;
        float p = hsc[bb][lane] * W_lin[lane] + hsc[bb][lane + 64] * W_lin[lane + 64];
        #pragma unroll
        for (int off = 32; off > 0; off >>= 1) p += __shfl_down(p, off, 64);
        if (lane == 0 && (b0 + bb) < B) out[b0 + bb] = p + b_lin[0];
    }
}

extern "C" void kernel_launch(void* const* d_in, const int* in_sizes, int n_in,
                              void* d_out, int out_size, void* d_ws, size_t ws_size,
                              hipStream_t stream) {
    const float* x     = (const float*)d_in[0];
    const float* W_ih  = (const float*)d_in[1];
    const float* W_hh  = (const float*)d_in[2];
    const float* b_ih  = (const float*)d_in[3];
    const float* b_hh  = (const float*)d_in[4];
    const float* W_lin = (const float*)d_in[5];
    const float* b_lin = (const float*)d_in[6];
    float* out = (float*)d_out;

    const int B = in_sizes[0] / (TT * II);          // 2048
    const int grid = (B + BT - 1) / BT;             // 512 blocks, 2 per CU
    lstm_r14<<<grid, NT, 0, stream>>>(x, W_ih, W_hh, b_ih, b_hh,
                                      W_lin, b_lin, out, B);
}

// Round 15
// 350.584 us; speedup vs baseline: 1.3840x; 1.1527x over previous
//
#include <hip/hip_runtime.h>

// LSTM B=2048,T=512,I=5,H=128 + linear -> [B,1], fp32 in/out.
// Round 15 = r12 revert (best, 344us) + SEED DISPLACEMENT. Serial-issue model
// (validated: MFMA 776 + trans@16cyc 640 + VALU ~100 = 1516 vs measured 1510):
// both pipes serialize under lockstep phases; all 4 de-phasing mechanisms
// (r7 K-split, r13 dataflow flags, r8/r9 + r14 block splits) regressed -
// spill, half-CUs, or 2x MFMA padding every time. The one free cut left: the
// 4 x/bias K16 MFMAs per wave-step have NO h dependency -> compute them as
// NEXT-step seeds during the cell phase (MFMA pipe idle there; mechanism
// correctness-proven in r13). acc is born from seed[g]; serial-path MFMA
// drops 698 -> 620 cyc/SIMD-step.
// Everything else = r12 exactly: 256 blocks x 8 batches, NT=512, row-permuted
// direct cell ownership (no shuffles), dbuf h + 1 barrier/step, folded
// activation scales, bias-1.0 xs column, peeled last step, f16 operands
// (absmax 4.882812e-4 exactly), waves_per_eu(2,2), SGB interleave hints.
// Dead-ends on record: BT=16 halves CUs; 1024-thr blocks pin VGPR@64->spill;
// NT=256 wf-doubling spills @128 VGPR + single-block residency; BT=4 doubles
// padding; K-split pacc +2e7 conflicts; in-block dataflow +660cyc poll cost.

#define HH 128
#define II 5
#define TT 512
#define BT 8
#define NT 512
#define KS 136             // hbuf row stride in f16
#define XT (TT * 8 + 8)    // xs per-batch stride in f16
#define HB (16 * KS)       // hbuf buffer stride in f16 elems

typedef __attribute__((ext_vector_type(8))) _Float16 half8;
typedef __attribute__((ext_vector_type(4))) _Float16 half4;
typedef __attribute__((ext_vector_type(4))) float f32x4;

#define SIG(u) __builtin_amdgcn_rcpf(1.0f + __builtin_amdgcn_exp2f(u))
#define MF32(A, B, C) __builtin_amdgcn_mfma_f32_16x16x32_f16((A), (B), (C), 0, 0, 0)
#define MF16(A, B, C) __builtin_amdgcn_mfma_f32_16x16x16f16((A), (B), (C), 0, 0, 0)
#define SGB(m, n) __builtin_amdgcn_sched_group_barrier((m), (n), 0)

// One timestep. PB = h read buffer (compile-time 0/1), LAST = peeled final.
// acc starts from seed[g] (x/bias MFMA computed during the PREVIOUS step's
// cell phase); this step's cell phase computes seeds for t+1 from prefetched ax4.
#define STEP(PB, LAST) {                                                        \
    const _Float16* hp = hrd + (PB) * HB;                                       \
    ah0 = *reinterpret_cast<const half8*>(hp);                                  \
    ah1 = *reinterpret_cast<const half8*>(hp + 32);                             \
    ah2 = *reinterpret_cast<const half8*>(hp + 64);                             \
    ah3 = *reinterpret_cast<const half8*>(hp + 96);                             \
    if (!(LAST)) {                      /* prefetch ax(t+1): static xs */       \
        xcur += xinc;                                                           \
        ax4 = *reinterpret_cast<const half4*>(xcur);                            \
    }                                                                           \
    /* gates i,f chains first (from seeds) */                                   \
    f32x4 a0 = seed[0], a1 = seed[1];                                           \
    a0 = MF32(ah0, wf[0][0], a0); a1 = MF32(ah0, wf[1][0], a1);                 \
    a0 = MF32(ah1, wf[0][1], a0); a1 = MF32(ah1, wf[1][1], a1);                 \
    a0 = MF32(ah2, wf[0][2], a0); a1 = MF32(ah2, wf[1][2], a1);                 \
    a0 = MF32(ah3, wf[0][3], a0); a1 = MF32(ah3, wf[1][3], a1);                 \
    /* i,f trans issue while g,o chains occupy the MFMA pipe */                 \
    float iv0 = SIG(a0[0]);                                                     \
    float iv1 = SIG(a0[1]);                                                     \
    float fv0 = SIG(a1[0]);                                                     \
    float fv1 = SIG(a1[1]);                                                     \
    f32x4 a2 = seed[2], a3 = seed[3];                                           \
    a2 = MF32(ah0, wf[2][0], a2); a3 = MF32(ah0, wf[3][0], a3);                 \
    a2 = MF32(ah1, wf[2][1], a2); a3 = MF32(ah1, wf[3][1], a3);                 \
    a2 = MF32(ah2, wf[2][2], a2); a3 = MF32(ah2, wf[3][2], a3);                 \
    a2 = MF32(ah3, wf[2][3], a2); a3 = MF32(ah3, wf[3][3], a3);                 \
    float gv0 = 1.0f - 2.0f * SIG(a2[0]);                                       \
    float ov0 = SIG(a3[0]);                                                     \
    cc0 = fv0 * cc0 + iv0 * gv0;                                                \
    float hv0 = ov0 * (1.0f - 2.0f * SIG(2.88539008f * cc0));                   \
    float gv1 = 1.0f - 2.0f * SIG(a2[1]);                                       \
    float ov1 = SIG(a3[1]);                                                     \
    cc1 = fv1 * cc1 + iv1 * gv1;                                                \
    float hv1 = ov1 * (1.0f - 2.0f * SIG(2.88539008f * cc1));                   \
    if (!(LAST)) {                      /* seeds for t+1: MFMA pipe idle here */\
        seed[0] = MF16(ax4, wfx[0], zero4);                                     \
        seed[1] = MF16(ax4, wfx[1], zero4);                                     \
        seed[2] = MF16(ax4, wfx[2], zero4);                                     \
        seed[3] = MF16(ax4, wfx[3], zero4);                                     \
    }                                                                           \
    if (LAST) {                                                                 \
        hsc[bcell][hcol] = hv0; hsc[bcell + 1][hcol] = hv1;                     \
    } else {                                                                    \
        _Float16* wp = hwr + ((PB) ^ 1) * HB;                                   \
        wp[0]  = (_Float16)hv0;                                                 \
        wp[KS] = (_Float16)hv1;                                                 \
    }                                                                           \
    /* ---- scheduling groups (soft; unmatched degrade to no-op) ------------ */\
    SGB(0x100, 5);     /* 4x ds_read_b128 (ah) + ax prefetch */                 \
    SGB(0x008, 8);     /* i,f MF32 chains */                                    \
    SGB(0x402, 14);    /* i,f sigmoids under g,o MFMA issue */                  \
    SGB(0x008, 8);     /* g,o MF32 chains */                                    \
    __syncthreads();                                                            \
}

__global__ __launch_bounds__(NT)
__attribute__((amdgpu_waves_per_eu(2, 2)))   // 256-VGPR budget: spill guard
void lstm_r15(const float* __restrict__ x,      // [B,T,I]
              const float* __restrict__ W_ih,   // [4H,I]
              const float* __restrict__ W_hh,   // [4H,H]
              const float* __restrict__ b_ih,   // [4H]
              const float* __restrict__ b_hh,   // [4H]
              const float* __restrict__ W_lin,  // [H]
              const float* __restrict__ b_lin,  // [1]
              float* __restrict__ out,          // [B]
              int B)
{
    __shared__ __align__(16) _Float16 hbuf[2][16][KS];  // rows 2,3 mod 4 stay 0
    __shared__ __align__(16) _Float16 zrow[KS];         // zeros for pad-row lanes
    __shared__ __align__(16) _Float16 xs[BT * XT];      // 65.7 KB staged x (f16)
    __shared__ float hsc[BT][HH + 4];                   // final fp32 h

    const int tid  = threadIdx.x;
    const int b0   = blockIdx.x * BT;
    const int lane = tid & 63;
    const int w    = tid >> 6;        // 0..7 -> col group
    const int n    = lane & 15;       // A row index / D col
    const int q    = lane >> 4;
    const int q8   = q * 8;
    const int hcol = w * 16 + n;      // this wave's gate columns

    // ---- W_hh frags, f16, B-layout (lane holds W^T[k=q8+e][col n]), scaled --
    half8 wf[4][4];
    half4 wfx[4];                     // x/bias chunk, K=16: k = q*4+e
    #pragma unroll
    for (int g = 0; g < 4; ++g) {
        const float sc = (g == 2) ? 2.88539008f : -1.44269504f;
        const int j = g * HH + hcol;
        #pragma unroll
        for (int kc = 0; kc < 4; ++kc) {
            const float* p = W_hh + (size_t)j * HH + kc * 32 + q8;
            #pragma unroll
            for (int e = 0; e < 8; ++e) wf[g][kc][e] = (_Float16)(p[e] * sc);
        }
        #pragma unroll
        for (int e = 0; e < 4; ++e) {
            const int k = q * 4 + e;
            float v = 0.0f;
            if (k < II)       v = W_ih[j * II + k];
            else if (k == II) v = b_ih[j] + b_hh[j];
            wfx[g][e] = (_Float16)(v * sc);
        }
    }

    // ---- zero LDS -----------------------------------------------------------
    for (int idx = tid; idx < 2 * 16 * KS; idx += NT)
        (&hbuf[0][0][0])[idx] = (_Float16)0.0f;
    if (tid < KS) zrow[tid] = (_Float16)0.0f;
    for (int idx = tid; idx < BT * XT; idx += NT)
        xs[idx] = (_Float16)0.0f;
    __syncthreads();

    // ---- stage x (f16) + constant-1.0 bias column in slot 5 -----------------
    {
        const int lb = tid & 63, bb = tid >> 6;     // 64 threads per batch
        if (b0 + bb < B) {
            const float* xb = x + (size_t)(b0 + bb) * TT * II;
            for (int e = lb * 4; e < TT * II; e += 256) {
                float4 v = *reinterpret_cast<const float4*>(xb + e);
                float vv[4] = {v.x, v.y, v.z, v.w};
                #pragma unroll
                for (int u = 0; u < 4; ++u) {
                    const int ee = e + u;
                    xs[bb * XT + (ee / 5) * 8 + (ee % 5)] = (_Float16)vv[u];
                }
            }
        }
        for (int s = tid; s < BT * TT; s += NT)
            xs[(s >> 9) * XT + (s & 511) * 8 + 5] = (_Float16)1.0f;
    }
    __syncthreads();

    // ---- loop-invariant state ----------------------------------------------
    // Row permutation (r10): batch b -> A-row rho(b) = (b>>1)*4 + (b&1);
    // C/D rows q*4+{0,1} = batches {2q, 2q+1} -> direct cell ownership.
    const int bcell = 2 * q;
    float cc0 = 0.f, cc1 = 0.f;
    const f32x4 zero4 = {0.f, 0.f, 0.f, 0.f};
    const bool xreal = ((n & 2) == 0);
    const int  bofn  = (n >> 2) * 2 + (n & 1);      // batch carried by A-row n
    const _Float16* hrd  = &hbuf[0][n][0] + q8;     // unconditional (pad rows = 0)
    _Float16*       hwr  = &hbuf[0][q * 4][0] + hcol;
    const _Float16* xcur = xreal ? (&xs[bofn * XT] + q * 4) : (&zrow[0] + q * 4);
    const int       xinc = xreal ? 8 : 0;

    half8 ah0, ah1, ah2, ah3;
    half4 ax4 = *reinterpret_cast<const half4*>(xcur);   // t=0 preload

    // seeds for t=0 (same mechanism as the in-loop seed displacement)
    f32x4 seed[4];
    seed[0] = MF16(ax4, wfx[0], zero4);
    seed[1] = MF16(ax4, wfx[1], zero4);
    seed[2] = MF16(ax4, wfx[2], zero4);
    seed[3] = MF16(ax4, wfx[3], zero4);

    #pragma unroll 1
    for (int k = 0; k < (TT - 2) / 2; ++k) {
        STEP(0, false);
        STEP(1, false);
    }
    STEP(0, false);     // t = 510
    STEP(1, true);      // t = 511, peeled: fp32 hsc write, no prefetch/seeds

    // ---- epilogue: out[b0+w] = hsc[w,:] . W_lin + b_lin ---------------------
    float p = hsc[w][lane] * W_lin[lane] + hsc[w][lane + 64] * W_lin[lane + 64];
    #pragma unroll
    for (int off = 32; off > 0; off >>= 1) p += __shfl_down(p, off, 64);
    if (lane == 0 && (b0 + w) < B) out[b0 + w] = p + b_lin[0];
}

extern "C" void kernel_launch(void* const* d_in, const int* in_sizes, int n_in,
                              void* d_out, int out_size, void* d_ws, size_t ws_size,
                              hipStream_t stream) {
    const float* x     = (const float*)d_in[0];
    const float* W_ih  = (const float*)d_in[1];
    const float* W_hh  = (const float*)d_in[2];
    const float* b_ih  = (const float*)d_in[3];
    const float* b_hh  = (const float*)d_in[4];
    const float* W_lin = (const float*)d_in[5];
    const float* b_lin = (const float*)d_in[6];
    float* out = (float*)d_out;

    const int B = in_sizes[0] / (TT * II);          // 2048
    const int grid = (B + BT - 1) / BT;             // 256 blocks, 1 per CU
    lstm_r15<<<grid, NT, 0, stream>>>(x, W_ih, W_hh, b_ih, b_hh,
                                      W_lin, b_lin, out, B);
}